// Round 1
// baseline (139.628 us; speedup 1.0000x reference)
//
#include <hip/hip_runtime.h>
#include <math.h>

// Problem constants (from reference setup_inputs)
#define B_    8
#define H_    32
#define D_    128
#define SMAX_ 4096
#define SCALE 0.5f

// Flash-decode partial kernel.
// grid = B*H*nsplit blocks, 256 threads (4 waves).
// Each 16-lane group processes one key position at a time:
//   lane (tid&15) owns d = (tid&15)*8 .. +7  (two float4 loads, 512B/group coalesced)
// Online softmax per group -> shfl merge across groups -> LDS merge across waves.
// Writes partial (m, l, acc[128]) per (bh, split) to ws, or final out if nsplit==1.
__global__ __launch_bounds__(256, 4)
void attn_partial(const float* __restrict__ q,
                  const float* __restrict__ knew,
                  const float* __restrict__ vnew,
                  const float* __restrict__ kcache,
                  const float* __restrict__ vcache,
                  const int* __restrict__ seqlen,
                  float* __restrict__ ws,
                  float* __restrict__ out,
                  int nsplit, int chunk)
{
    const int blk   = blockIdx.x;
    const int split = blk % nsplit;
    const int bh    = blk / nsplit;
    const int h     = bh & (H_ - 1);
    const int b     = bh / H_;

    const int sl    = seqlen[b];
    const int total = sl + 1;                 // attend positions 0..sl (sl == new token)
    const int cs    = split * chunk;
    const int ce    = min(cs + chunk, total);

    const int tid    = threadIdx.x;
    const int lane16 = tid & 15;              // d-slice owner within group
    const int gid    = tid >> 4;              // 0..15 position-group id within block

    // q fragment: 8 floats per lane
    const int qbase = (b * H_ + h) * D_ + lane16 * 8;
    float qf[8];
    {
        float4 q0 = *(const float4*)(q + qbase);
        float4 q1 = *(const float4*)(q + qbase + 4);
        qf[0]=q0.x; qf[1]=q0.y; qf[2]=q0.z; qf[3]=q0.w;
        qf[4]=q1.x; qf[5]=q1.y; qf[6]=q1.z; qf[7]=q1.w;
    }

    // -1e30 sentinel (NOT -inf: exp(-inf - -inf) = NaN when merging empty groups)
    float m = -1e30f, l = 0.f;
    float acc[8];
    #pragma unroll
    for (int j = 0; j < 8; ++j) acc[j] = 0.f;

    const size_t cbase = (size_t)b * SMAX_ * (H_ * D_) + (size_t)h * D_ + (size_t)(lane16 * 8);

    for (int p = cs + gid; p < ce; p += 16) {
        const float* kp;
        const float* vp;
        if (p == sl) {                       // the appended token comes from k/v inputs
            kp = knew + qbase;
            vp = vnew + qbase;
        } else {
            size_t off = cbase + (size_t)p * (H_ * D_);
            kp = kcache + off;
            vp = vcache + off;
        }
        float4 k0 = *(const float4*)(kp);
        float4 k1 = *(const float4*)(kp + 4);
        float4 v0 = *(const float4*)(vp);
        float4 v1 = *(const float4*)(vp + 4);

        float s = qf[0]*k0.x + qf[1]*k0.y + qf[2]*k0.z + qf[3]*k0.w
                + qf[4]*k1.x + qf[5]*k1.y + qf[6]*k1.z + qf[7]*k1.w;
        // reduce partial dot across the 16-lane group
        s += __shfl_xor(s, 1);
        s += __shfl_xor(s, 2);
        s += __shfl_xor(s, 4);
        s += __shfl_xor(s, 8);
        s *= SCALE;

        float mn = fmaxf(m, s);
        float sc = __expf(m - mn);
        float pr = __expf(s - mn);
        m = mn;
        l = l * sc + pr;
        acc[0] = fmaf(pr, v0.x, acc[0]*sc);
        acc[1] = fmaf(pr, v0.y, acc[1]*sc);
        acc[2] = fmaf(pr, v0.z, acc[2]*sc);
        acc[3] = fmaf(pr, v0.w, acc[3]*sc);
        acc[4] = fmaf(pr, v1.x, acc[4]*sc);
        acc[5] = fmaf(pr, v1.y, acc[5]*sc);
        acc[6] = fmaf(pr, v1.z, acc[6]*sc);
        acc[7] = fmaf(pr, v1.w, acc[7]*sc);
    }

    // merge the 4 groups within each wave (lanes with equal (tid&15) hold same d-slice)
    #pragma unroll
    for (int off = 16; off <= 32; off <<= 1) {
        float m2 = __shfl_xor(m, off);
        float l2 = __shfl_xor(l, off);
        float a2[8];
        #pragma unroll
        for (int j = 0; j < 8; ++j) a2[j] = __shfl_xor(acc[j], off);
        float mn = fmaxf(m, m2);
        float s1 = __expf(m - mn);
        float s2 = __expf(m2 - mn);
        l = l * s1 + l2 * s2;
        #pragma unroll
        for (int j = 0; j < 8; ++j) acc[j] = acc[j]*s1 + a2[j]*s2;
        m = mn;
    }

    // merge the 4 waves via LDS
    __shared__ float sm_m[4];
    __shared__ float sm_l[4];
    __shared__ float sm_acc[4][D_];
    const int w    = tid >> 6;
    const int lane = tid & 63;
    if (lane < 16) {
        if (lane == 0) { sm_m[w] = m; sm_l[w] = l; }
        #pragma unroll
        for (int j = 0; j < 8; ++j) sm_acc[w][lane16*8 + j] = acc[j];
    }
    __syncthreads();

    if (tid < D_) {
        float m0 = sm_m[0], m1 = sm_m[1], m2 = sm_m[2], m3 = sm_m[3];
        float mt = fmaxf(fmaxf(m0, m1), fmaxf(m2, m3));
        float e0 = __expf(m0 - mt), e1 = __expf(m1 - mt);
        float e2 = __expf(m2 - mt), e3 = __expf(m3 - mt);
        float lt = sm_l[0]*e0 + sm_l[1]*e1 + sm_l[2]*e2 + sm_l[3]*e3;
        float a  = sm_acc[0][tid]*e0 + sm_acc[1][tid]*e1
                 + sm_acc[2][tid]*e2 + sm_acc[3][tid]*e3;
        if (nsplit == 1) {
            out[bh * D_ + tid] = a / lt;     // lt >= exp(0) contribution; total>=1 always
        } else {
            float* wsp = ws + (size_t)blk * (D_ + 2);
            if (tid == 0) { wsp[0] = mt; wsp[1] = lt; }
            wsp[2 + tid] = a;
        }
    }
}

// Combine partials across splits. grid = B*H blocks, 128 threads.
__global__ __launch_bounds__(128)
void attn_combine(const float* __restrict__ ws, float* __restrict__ out, int nsplit)
{
    const int bh = blockIdx.x;
    const int d  = threadIdx.x;
    const float* base = ws + (size_t)bh * nsplit * (D_ + 2);

    float mt = -1e30f;
    for (int s = 0; s < nsplit; ++s) mt = fmaxf(mt, base[(size_t)s * (D_ + 2)]);
    float lt = 0.f, a = 0.f;
    for (int s = 0; s < nsplit; ++s) {
        const float* p = base + (size_t)s * (D_ + 2);
        float e = __expf(p[0] - mt);
        lt += p[1] * e;
        a  += p[2 + d] * e;
    }
    out[bh * D_ + d] = a / lt;
}

extern "C" void kernel_launch(void* const* d_in, const int* in_sizes, int n_in,
                              void* d_out, int out_size, void* d_ws, size_t ws_size,
                              hipStream_t stream) {
    const float* q  = (const float*)d_in[0];
    const float* k  = (const float*)d_in[1];
    const float* v  = (const float*)d_in[2];
    const float* kc = (const float*)d_in[3];
    const float* vc = (const float*)d_in[4];
    const int*   sl = (const int*)d_in[5];
    float* out = (float*)d_out;
    float* ws  = (float*)d_ws;

    // split-K factor: 16 gives 4096 blocks (good occupancy + load balance across
    // varying seqlen). Degrade if workspace is unexpectedly small.
    int nsplit = 16;
    while (nsplit > 1 &&
           (size_t)B_ * H_ * nsplit * (D_ + 2) * sizeof(float) > ws_size) {
        nsplit >>= 1;
    }
    const int chunk = (SMAX_ + nsplit - 1) / nsplit;
    const int nblk  = B_ * H_ * nsplit;

    attn_partial<<<nblk, 256, 0, stream>>>(q, k, v, kc, vc, sl, ws, out, nsplit, chunk);
    if (nsplit > 1) {
        attn_combine<<<B_ * H_, 128, 0, stream>>>(ws, out, nsplit);
    }
}